// Round 1
// baseline (348.801 us; speedup 1.0000x reference)
//
#include <hip/hip_runtime.h>

#define NNODES 50000
#define NEDGES 800000
#define DIM 96
#define LLDIM 64
#define NRELS 3            // metapath relations 0,1,2
#define SCAN_N (NRELS * NNODES)

// ---------------- CSR build ----------------

__global__ void hist_kernel(const int* __restrict__ ei, const int* __restrict__ et,
                            int* __restrict__ deg) {
    int e = blockIdx.x * 256 + threadIdx.x;
    if (e >= NEDGES) return;
    int r = et[e];
    if (r < NRELS) atomicAdd(&deg[r * NNODES + ei[e]], 1);
}

// block-local exclusive scan over 1024 items (256 thr x 4), block totals to partials
__global__ void scan1_kernel(const int* __restrict__ in, int* __restrict__ out,
                             int* __restrict__ partials, int n) {
    __shared__ int sdata[256];
    int tid = threadIdx.x;
    int base = blockIdx.x * 1024 + tid * 4;
    int v0 = (base + 0 < n) ? in[base + 0] : 0;
    int v1 = (base + 1 < n) ? in[base + 1] : 0;
    int v2 = (base + 2 < n) ? in[base + 2] : 0;
    int v3 = (base + 3 < n) ? in[base + 3] : 0;
    int tsum = v0 + v1 + v2 + v3;
    sdata[tid] = tsum;
    __syncthreads();
    for (int off = 1; off < 256; off <<= 1) {
        int x = sdata[tid];
        int y = (tid >= off) ? sdata[tid - off] : 0;
        __syncthreads();
        sdata[tid] = x + y;
        __syncthreads();
    }
    int excl = sdata[tid] - tsum;
    if (tid == 255) partials[blockIdx.x] = sdata[255];
    if (base + 0 < n) out[base + 0] = excl;
    excl += v0;
    if (base + 1 < n) out[base + 1] = excl;
    excl += v1;
    if (base + 2 < n) out[base + 2] = excl;
    excl += v2;
    if (base + 3 < n) out[base + 3] = excl;
}

__global__ void scan2_kernel(int* __restrict__ partials, int nb) {
    __shared__ int sdata[256];
    int tid = threadIdx.x;
    int v = (tid < nb) ? partials[tid] : 0;
    sdata[tid] = v;
    __syncthreads();
    for (int off = 1; off < 256; off <<= 1) {
        int x = sdata[tid];
        int y = (tid >= off) ? sdata[tid - off] : 0;
        __syncthreads();
        sdata[tid] = x + y;
        __syncthreads();
    }
    partials[tid] = sdata[tid] - v;   // exclusive
}

__global__ void scan3_kernel(int* __restrict__ out, const int* __restrict__ partials, int n) {
    int idx = blockIdx.x * 256 + threadIdx.x;
    if (idx < n) out[idx] += partials[idx >> 10];
}

// cursor (row_end) pre-initialized to row_start; after fill it holds row ends.
__global__ void fill_kernel(const int* __restrict__ ei, const int* __restrict__ et,
                            int* __restrict__ cursor, int* __restrict__ col) {
    int e = blockIdx.x * 256 + threadIdx.x;
    if (e >= NEDGES) return;
    int r = et[e];
    if (r < NRELS) {
        int pos = atomicAdd(&cursor[r * NNODES + ei[e]], 1);
        col[pos] = ei[NEDGES + e];
    }
}

// ---------------- per-layer aggregate (gather, mean folded in) ----------------

__global__ void gather_kernel(const float* __restrict__ h, const int* __restrict__ row_start,
                              const int* __restrict__ row_end, const int* __restrict__ col,
                              float* __restrict__ agg, int rel) {
    int g = blockIdx.x * 8 + (threadIdx.x >> 5);   // node id
    if (g >= NNODES) return;
    int lane = threadIdx.x & 31;
    int s = row_start[rel * NNODES + g];
    int e = row_end[rel * NNODES + g];
    float a0 = 0.0f, a1 = 0.0f, a2 = 0.0f;
    for (int i = s; i < e; ++i) {
        int d = col[i];
        const float* hr = h + (size_t)d * DIM;
        a0 += hr[lane];
        a1 += hr[lane + 32];
        a2 += hr[lane + 64];
    }
    float scl = 1.0f / fmaxf((float)(e - s), 1.0f);
    float* ar = agg + (size_t)g * DIM;
    ar[lane] = a0 * scl;
    ar[lane + 32] = a1 * scl;
    ar[lane + 64] = a2 * scl;
}

// ---------------- layer GEMM: out = relu(agg@W + h@R + b) ----------------
// New structure ("SGPR-W"): 64-node tile, 3 waves x 32 cols, lane = node.
// A staged transposed in LDS [k][node] (stride 65: conflict-free reads);
// W row values are wave-uniform -> scalar loads (SGPR broadcast), so the
// LDS pipe only carries 1 ds_read_b32 per 32 FMAs (VALU-bound, not LDS-bound).

__global__ __launch_bounds__(192) void layer_kernel(
    const float* __restrict__ h, const float* __restrict__ agg,
    const float* __restrict__ W, const float* __restrict__ R,
    const float* __restrict__ b, float* __restrict__ out) {
    __shared__ float At[96 * 65];          // [k][node], padded stride 65 (24.4 KB)
    const int tid  = threadIdx.x;
    const int lane = tid & 63;
    const int wv   = tid >> 6;             // 0..2
    const int cb   = __builtin_amdgcn_readfirstlane(wv * 32);   // wave's col base
    const int n0   = blockIdx.x * 64;
    const int node = n0 + lane;
    const bool valid = node < NNODES;

    float acc[32];
#pragma unroll
    for (int c = 0; c < 32; ++c) acc[c] = 0.0f;

    const size_t tile_base = (size_t)n0 * DIM;           // float index of tile start
    const size_t max_off   = (size_t)NNODES * DIM - 4;   // last aligned float4 start

    for (int ph = 0; ph < 2; ++ph) {
        const float* src = ph ? h : agg;
        const float* wb  = (ph ? R : W) + cb;
        __syncthreads();                      // previous compute done reading At
        // stage 64x96 tile transposed; tile is contiguous so loads are coalesced.
        // float4 #g covers (node = g/24, cols (g%24)*4 ..+3)
#pragma unroll
        for (int j = 0; j < 8; ++j) {
            int g = tid + j * 192;
            size_t off = tile_base + (size_t)g * 4;
            if (off > max_off) off = max_off;             // clamp (stores guarded)
            float4 v = *(const float4*)(src + off);
            int nd = g / 24;
            int c  = (g % 24) * 4;
            At[(c + 0) * 65 + nd] = v.x;
            At[(c + 1) * 65 + nd] = v.y;
            At[(c + 2) * 65 + nd] = v.z;
            At[(c + 3) * 65 + nd] = v.w;
        }
        __syncthreads();
#pragma unroll 2
        for (int k = 0; k < 96; ++k) {
            float a = At[k * 65 + lane];               // 1 ds_read_b32, conflict-free
            const float* wr = wb + k * DIM;            // uniform address -> s_load
#pragma unroll
            for (int c = 0; c < 32; ++c)
                acc[c] = fmaf(a, wr[c], acc[c]);       // v_fmac v, s_w, v_a
        }
    }

    if (valid) {
        float* orow = out + (size_t)node * DIM + cb;
        const float* brow = b + cb;
#pragma unroll
        for (int c4 = 0; c4 < 8; ++c4) {
            float4 r;
            r.x = fmaxf(acc[c4 * 4 + 0] + brow[c4 * 4 + 0], 0.0f);
            r.y = fmaxf(acc[c4 * 4 + 1] + brow[c4 * 4 + 1], 0.0f);
            r.z = fmaxf(acc[c4 * 4 + 2] + brow[c4 * 4 + 2], 0.0f);
            r.w = fmaxf(acc[c4 * 4 + 3] + brow[c4 * 4 + 3], 0.0f);
            *(float4*)(orow + c4 * 4) = r;
        }
    }
}

// ---------------- final linear: out = h @ lin_w + lin_b (no relu) ----------------
// Same SGPR-W template: 64-node tile, 2 waves x 32 cols, K = 96 single phase.

__global__ __launch_bounds__(128) void final_kernel(
    const float* __restrict__ h, const float* __restrict__ LW,
    const float* __restrict__ LB, float* __restrict__ out) {
    __shared__ float At[96 * 65];
    const int tid  = threadIdx.x;
    const int lane = tid & 63;
    const int wv   = tid >> 6;             // 0..1
    const int cb   = __builtin_amdgcn_readfirstlane(wv * 32);
    const int n0   = blockIdx.x * 64;
    const int node = n0 + lane;
    const bool valid = node < NNODES;

    float acc[32];
#pragma unroll
    for (int c = 0; c < 32; ++c) acc[c] = 0.0f;

    const size_t tile_base = (size_t)n0 * DIM;
    const size_t max_off   = (size_t)NNODES * DIM - 4;

#pragma unroll
    for (int j = 0; j < 12; ++j) {
        int g = tid + j * 128;
        size_t off = tile_base + (size_t)g * 4;
        if (off > max_off) off = max_off;
        float4 v = *(const float4*)(h + off);
        int nd = g / 24;
        int c  = (g % 24) * 4;
        At[(c + 0) * 65 + nd] = v.x;
        At[(c + 1) * 65 + nd] = v.y;
        At[(c + 2) * 65 + nd] = v.z;
        At[(c + 3) * 65 + nd] = v.w;
    }
    __syncthreads();
#pragma unroll 2
    for (int k = 0; k < 96; ++k) {
        float a = At[k * 65 + lane];
        const float* wr = LW + k * LLDIM + cb;         // uniform -> s_load
#pragma unroll
        for (int c = 0; c < 32; ++c)
            acc[c] = fmaf(a, wr[c], acc[c]);
    }

    if (valid) {
        float* orow = out + (size_t)node * LLDIM + cb;
        const float* brow = LB + cb;
#pragma unroll
        for (int c4 = 0; c4 < 8; ++c4) {
            float4 r;
            r.x = acc[c4 * 4 + 0] + brow[c4 * 4 + 0];
            r.y = acc[c4 * 4 + 1] + brow[c4 * 4 + 1];
            r.z = acc[c4 * 4 + 2] + brow[c4 * 4 + 2];
            r.w = acc[c4 * 4 + 3] + brow[c4 * 4 + 3];
            *(float4*)(orow + c4 * 4) = r;
        }
    }
}

extern "C" void kernel_launch(void* const* d_in, const int* in_sizes, int n_in,
                              void* d_out, int out_size, void* d_ws, size_t ws_size,
                              hipStream_t stream) {
    const float* x     = (const float*)d_in[0];
    const int*   ei    = (const int*)d_in[1];
    const int*   et    = (const int*)d_in[2];
    const float* w1    = (const float*)d_in[3];
    const float* root1 = (const float*)d_in[4];
    const float* b1    = (const float*)d_in[5];
    const float* w2    = (const float*)d_in[6];
    const float* root2 = (const float*)d_in[7];
    const float* b2    = (const float*)d_in[8];
    const float* lin_w = (const float*)d_in[9];
    const float* lin_b = (const float*)d_in[10];

    float* bufA = (float*)d_ws;                      // N*96
    float* bufB = bufA + (size_t)NNODES * DIM;       // N*96
    float* agg  = bufB + (size_t)NNODES * DIM;       // N*96
    int* deg       = (int*)(agg + (size_t)NNODES * DIM);
    int* row_start = deg + SCAN_N;
    int* row_end   = row_start + SCAN_N;
    int* col       = row_end + SCAN_N;               // up to NEDGES
    int* partials  = col + NEDGES;                   // 256

    const int edge_blocks = (NEDGES + 255) / 256;
    const int scan_blocks = (SCAN_N + 1023) / 1024;  // 147
    const int node_tiles  = (NNODES + 63) / 64;      // 782
    const int gath_blocks = (NNODES + 7) / 8;        // 6250

    // ---- CSR build (edge structure is identical for all 3 layers) ----
    hipMemsetAsync(deg, 0, SCAN_N * sizeof(int), stream);
    hist_kernel<<<edge_blocks, 256, 0, stream>>>(ei, et, deg);
    scan1_kernel<<<scan_blocks, 256, 0, stream>>>(deg, row_start, partials, SCAN_N);
    scan2_kernel<<<1, 256, 0, stream>>>(partials, scan_blocks);
    scan3_kernel<<<(SCAN_N + 255) / 256, 256, 0, stream>>>(row_start, partials, SCAN_N);
    hipMemcpyAsync(row_end, row_start, SCAN_N * sizeof(int), hipMemcpyDeviceToDevice, stream);
    fill_kernel<<<edge_blocks, 256, 0, stream>>>(ei, et, row_end, col);

    // ---- Layer 0: rel 0, w1[0], root1, b1 :  x -> bufA ----
    gather_kernel<<<gath_blocks, 256, 0, stream>>>(x, row_start, row_end, col, agg, 0);
    layer_kernel<<<node_tiles, 192, 0, stream>>>(x, agg, w1, root1, b1, bufA);

    // ---- Layer 1: rel 1, w2[1], root2, b2 :  bufA -> bufB ----
    gather_kernel<<<gath_blocks, 256, 0, stream>>>(bufA, row_start, row_end, col, agg, 1);
    layer_kernel<<<node_tiles, 192, 0, stream>>>(bufA, agg, w2 + (size_t)1 * DIM * DIM,
                                                 root2, b2, bufB);

    // ---- Layer 2: rel 2, w2[2], root2, b2 :  bufB -> bufA ----
    gather_kernel<<<gath_blocks, 256, 0, stream>>>(bufB, row_start, row_end, col, agg, 2);
    layer_kernel<<<node_tiles, 192, 0, stream>>>(bufB, agg, w2 + (size_t)2 * DIM * DIM,
                                                 root2, b2, bufA);

    // ---- Final linear: bufA -> d_out ----
    final_kernel<<<node_tiles, 128, 0, stream>>>(bufA, lin_w, lin_b, (float*)d_out);
}

// Round 2
// 282.111 us; speedup vs baseline: 1.2364x; 1.2364x over previous
//
#include <hip/hip_runtime.h>

#define NNODES 50000
#define NEDGES 800000
#define DIM 96
#define LLDIM 64
#define NRELS 3            // metapath relations 0,1,2
#define SCAN_N (NRELS * NNODES)
#define BT_LAYER_STRIDE (2 * 96 * 192)   // ushorts per layer (hi plane + lo plane)

typedef __attribute__((ext_vector_type(8))) short bf16x8;
typedef __attribute__((ext_vector_type(4))) float f32x4;

__device__ __forceinline__ unsigned short f2bf(float x) {
    union { float f; unsigned u; } v; v.f = x;
    unsigned r = v.u + 0x7fffu + ((v.u >> 16) & 1u);   // round-to-nearest-even
    return (unsigned short)(r >> 16);
}
__device__ __forceinline__ float bf2f(unsigned short b) {
    union { unsigned u; float f; } v; v.u = ((unsigned)b) << 16;
    return v.f;
}

// ---------------- CSR build ----------------

__global__ void hist_kernel(const int* __restrict__ ei, const int* __restrict__ et,
                            int* __restrict__ deg) {
    int e = blockIdx.x * 256 + threadIdx.x;
    if (e >= NEDGES) return;
    int r = et[e];
    if (r < NRELS) atomicAdd(&deg[r * NNODES + ei[e]], 1);
}

__global__ void scan1_kernel(const int* __restrict__ in, int* __restrict__ out,
                             int* __restrict__ partials, int n) {
    __shared__ int sdata[256];
    int tid = threadIdx.x;
    int base = blockIdx.x * 1024 + tid * 4;
    int v0 = (base + 0 < n) ? in[base + 0] : 0;
    int v1 = (base + 1 < n) ? in[base + 1] : 0;
    int v2 = (base + 2 < n) ? in[base + 2] : 0;
    int v3 = (base + 3 < n) ? in[base + 3] : 0;
    int tsum = v0 + v1 + v2 + v3;
    sdata[tid] = tsum;
    __syncthreads();
    for (int off = 1; off < 256; off <<= 1) {
        int x = sdata[tid];
        int y = (tid >= off) ? sdata[tid - off] : 0;
        __syncthreads();
        sdata[tid] = x + y;
        __syncthreads();
    }
    int excl = sdata[tid] - tsum;
    if (tid == 255) partials[blockIdx.x] = sdata[255];
    if (base + 0 < n) out[base + 0] = excl;
    excl += v0;
    if (base + 1 < n) out[base + 1] = excl;
    excl += v1;
    if (base + 2 < n) out[base + 2] = excl;
    excl += v2;
    if (base + 3 < n) out[base + 3] = excl;
}

__global__ void scan2_kernel(int* __restrict__ partials, int nb) {
    __shared__ int sdata[256];
    int tid = threadIdx.x;
    int v = (tid < nb) ? partials[tid] : 0;
    sdata[tid] = v;
    __syncthreads();
    for (int off = 1; off < 256; off <<= 1) {
        int x = sdata[tid];
        int y = (tid >= off) ? sdata[tid - off] : 0;
        __syncthreads();
        sdata[tid] = x + y;
        __syncthreads();
    }
    partials[tid] = sdata[tid] - v;   // exclusive
}

__global__ void scan3_kernel(int* __restrict__ out, const int* __restrict__ partials, int n) {
    int idx = blockIdx.x * 256 + threadIdx.x;
    if (idx < n) out[idx] += partials[idx >> 10];
}

__global__ void fill_kernel(const int* __restrict__ ei, const int* __restrict__ et,
                            int* __restrict__ cursor, int* __restrict__ col) {
    int e = blockIdx.x * 256 + threadIdx.x;
    if (e >= NEDGES) return;
    int r = et[e];
    if (r < NRELS) {
        int pos = atomicAdd(&cursor[r * NNODES + ei[e]], 1);
        col[pos] = ei[NEDGES + e];
    }
}

// ---------------- per-layer aggregate (gather, mean folded in) ----------------

__global__ void gather_kernel(const float* __restrict__ h, const int* __restrict__ row_start,
                              const int* __restrict__ row_end, const int* __restrict__ col,
                              float* __restrict__ agg, int rel) {
    int g = blockIdx.x * 8 + (threadIdx.x >> 5);   // node id
    if (g >= NNODES) return;
    int lane = threadIdx.x & 31;
    int s = row_start[rel * NNODES + g];
    int e = row_end[rel * NNODES + g];
    float a0 = 0.0f, a1 = 0.0f, a2 = 0.0f;
    for (int i = s; i < e; ++i) {
        int d = col[i];
        const float* hr = h + (size_t)d * DIM;
        a0 += hr[lane];
        a1 += hr[lane + 32];
        a2 += hr[lane + 64];
    }
    float scl = 1.0f / fmaxf((float)(e - s), 1.0f);
    float* ar = agg + (size_t)g * DIM;
    ar[lane] = a0 * scl;
    ar[lane + 32] = a1 * scl;
    ar[lane + 64] = a2 * scl;
}

// ---------------- weight prep: B^T split into bf16 hi/lo planes ----------------
// Per layer l: Bcat = [W_l (96x96) ; R_l (96x96)] stacked on K (192 x 96).
// Store BT_hi[c][k], BT_lo[c][k] as [96][192] ushort planes (hi then lo).

__global__ void prep_kernel(const float* __restrict__ w1, const float* __restrict__ root1,
                            const float* __restrict__ w2, const float* __restrict__ root2,
                            unsigned short* __restrict__ bt) {
    int idx = blockIdx.x * 256 + threadIdx.x;
    if (idx >= 3 * 96 * 192) return;
    int l = idx / (96 * 192);
    int rem = idx % (96 * 192);
    int c = rem / 192;
    int k = rem % 192;
    const float* Wm;
    const float* Rm;
    if (l == 0) { Wm = w1; Rm = root1; }                       // w1[rel=0], root1
    else        { Wm = w2 + (size_t)l * 96 * 96; Rm = root2; } // w2[l], root2
    float v = (k < 96) ? Wm[(size_t)k * 96 + c] : Rm[(size_t)(k - 96) * 96 + c];
    unsigned short hi = f2bf(v);
    unsigned short lo = f2bf(v - bf2f(hi));
    unsigned short* base = bt + (size_t)l * BT_LAYER_STRIDE;
    base[(size_t)c * 192 + k] = hi;                 // hi plane
    base[(size_t)96 * 192 + (size_t)c * 192 + k] = lo;   // lo plane
}

// ---------------- layer GEMM via split-bf16 MFMA ----------------
// out = relu([agg|h] @ [W;R] + b), K=192 in 2 phases of 96 (agg@W, h@R).
// Block: 256 thr (4 waves), tile 64 nodes x 96 cols; wave = 32 nodes x 48 cols
// = 2x3 tiles of mfma_f32_16x16x32_bf16. Three split terms: AhBh + AlBh + AhBl
// (lo*lo dropped, ~2^-16 relative error). LDS rows padded to 104 bf16 (208 B,
// 16B-aligned, 52-word stride -> <=2-way banks = free).

__global__ __launch_bounds__(256) void layer_mfma_kernel(
    const float* __restrict__ h, const float* __restrict__ agg,
    const unsigned short* __restrict__ bt,   // layer's hi plane; lo at +96*192
    const float* __restrict__ b, float* __restrict__ out) {
    __shared__ unsigned short Ah[64 * 104];
    __shared__ unsigned short Al[64 * 104];
    __shared__ unsigned short Bh[96 * 104];
    __shared__ unsigned short Bl[96 * 104];
    const int tid = threadIdx.x;
    const int lane = tid & 63;
    const int w = tid >> 6;                 // 0..3
    const int r = lane & 15;                // row-in-tile (A) / col-in-tile (B)
    const int g = lane >> 4;                // k-group 0..3
    const int rb_base = (w >> 1) * 32;      // 0 or 32
    const int ct_base = (w & 1) * 48;       // 0 or 48
    const int n0 = blockIdx.x * 64;
    const unsigned short* bt_lo = bt + 96 * 192;

    f32x4 acc[2][3];
#pragma unroll
    for (int i = 0; i < 2; ++i)
#pragma unroll
        for (int j = 0; j < 3; ++j) acc[i][j] = (f32x4){0.f, 0.f, 0.f, 0.f};

    for (int ph = 0; ph < 2; ++ph) {
        const float* src = ph ? h : agg;
        __syncthreads();                      // previous phase done reading LDS
        // stage A (64x96 fp32 -> hi/lo bf16, transpose-free: [node][k])
#pragma unroll
        for (int j = 0; j < 6; ++j) {
            int idx = tid + j * 256;          // 0..1535 float4s
            int nd = idx / 24;
            int kq = idx % 24;
            int node = n0 + nd;
            if (node >= NNODES) node = NNODES - 1;   // stores guarded later
            float4 v = *(const float4*)(src + (size_t)node * DIM + kq * 4);
            unsigned short h0 = f2bf(v.x), h1 = f2bf(v.y), h2 = f2bf(v.z), h3 = f2bf(v.w);
            *(ushort4*)&Ah[nd * 104 + kq * 4] = make_ushort4(h0, h1, h2, h3);
            unsigned short l0 = f2bf(v.x - bf2f(h0));
            unsigned short l1 = f2bf(v.y - bf2f(h1));
            unsigned short l2 = f2bf(v.z - bf2f(h2));
            unsigned short l3 = f2bf(v.w - bf2f(h3));
            *(ushort4*)&Al[nd * 104 + kq * 4] = make_ushort4(l0, l1, l2, l3);
        }
        // stage B^T slice for this phase (2 planes x 96 cols x 96 k)
#pragma unroll
        for (int j = 0; j < 9; ++j) {
            int idx = tid + j * 256;          // 0..2303 uint4s
            int plane = idx / 1152;
            int rem = idx - plane * 1152;
            int c = rem / 12;
            int kq = rem % 12;
            const unsigned short* sp = (plane ? bt_lo : bt) + (size_t)c * 192 + ph * 96 + kq * 8;
            unsigned short* dp = (plane ? Bl : Bh) + c * 104 + kq * 8;
            *(uint4*)dp = *(const uint4*)sp;
        }
        __syncthreads();
#pragma unroll
        for (int ks = 0; ks < 3; ++ks) {
            const int ko = ks * 32 + g * 8;
            bf16x8 a0h = *(const bf16x8*)&Ah[(rb_base + r) * 104 + ko];
            bf16x8 a1h = *(const bf16x8*)&Ah[(rb_base + 16 + r) * 104 + ko];
            bf16x8 a0l = *(const bf16x8*)&Al[(rb_base + r) * 104 + ko];
            bf16x8 a1l = *(const bf16x8*)&Al[(rb_base + 16 + r) * 104 + ko];
#pragma unroll
            for (int ct = 0; ct < 3; ++ct) {
                int c = ct_base + ct * 16 + r;
                bf16x8 bhv = *(const bf16x8*)&Bh[c * 104 + ko];
                bf16x8 blv = *(const bf16x8*)&Bl[c * 104 + ko];
                acc[0][ct] = __builtin_amdgcn_mfma_f32_16x16x32_bf16(a0h, bhv, acc[0][ct], 0, 0, 0);
                acc[1][ct] = __builtin_amdgcn_mfma_f32_16x16x32_bf16(a1h, bhv, acc[1][ct], 0, 0, 0);
                acc[0][ct] = __builtin_amdgcn_mfma_f32_16x16x32_bf16(a0l, bhv, acc[0][ct], 0, 0, 0);
                acc[1][ct] = __builtin_amdgcn_mfma_f32_16x16x32_bf16(a1l, bhv, acc[1][ct], 0, 0, 0);
                acc[0][ct] = __builtin_amdgcn_mfma_f32_16x16x32_bf16(a0h, blv, acc[0][ct], 0, 0, 0);
                acc[1][ct] = __builtin_amdgcn_mfma_f32_16x16x32_bf16(a1h, blv, acc[1][ct], 0, 0, 0);
            }
        }
    }

    // epilogue: C/D layout (verified): col = lane&15, row = (lane>>4)*4 + j
#pragma unroll
    for (int ct = 0; ct < 3; ++ct) {
        int col = ct_base + ct * 16 + r;
        float bias = b[col];
#pragma unroll
        for (int rbi = 0; rbi < 2; ++rbi) {
            int row0 = n0 + rb_base + rbi * 16 + g * 4;
#pragma unroll
            for (int j = 0; j < 4; ++j) {
                int node = row0 + j;
                if (node < NNODES)
                    out[(size_t)node * DIM + col] = fmaxf(acc[rbi][ct][j] + bias, 0.0f);
            }
        }
    }
}

// ---------------- final linear: out = h @ lin_w + lin_b (round-0 version) ----------------

__global__ __launch_bounds__(256) void final_kernel(
    const float* __restrict__ h, const float* __restrict__ LW,
    const float* __restrict__ LB, float* __restrict__ out) {
    __shared__ __align__(16) float Alds[32][68];
    __shared__ __align__(16) float Wlds[32][LLDIM];
    int tid = threadIdx.x;
    int q = tid % 16;        // col quad
    int nb = tid / 16;       // 0..15
    int n0 = blockIdx.x * 64;

    float acc[4][4];
#pragma unroll
    for (int j = 0; j < 4; ++j)
#pragma unroll
        for (int c = 0; c < 4; ++c) acc[j][c] = 0.0f;

    for (int chunk = 0; chunk < 3; ++chunk) {
        int kc = chunk * 32;
        __syncthreads();
        for (int idx = tid; idx < 512; idx += 256) {
            int row = idx >> 3;
            int kq = idx & 7;
            int rnode = n0 + row;
            if (rnode >= NNODES) rnode = NNODES - 1;
            float4 v = *(const float4*)(h + (size_t)rnode * DIM + kc + kq * 4);
            int kk = kq * 4;
            Alds[kk + 0][row] = v.x;
            Alds[kk + 1][row] = v.y;
            Alds[kk + 2][row] = v.z;
            Alds[kk + 3][row] = v.w;
        }
        for (int idx = tid; idx < 512; idx += 256) {
            int kr = idx / 16;
            int cq = idx % 16;
            *(float4*)&Wlds[kr][cq * 4] =
                *(const float4*)(LW + (size_t)(kc + kr) * LLDIM + cq * 4);
        }
        __syncthreads();
#pragma unroll 8
        for (int k = 0; k < 32; ++k) {
            float4 w4 = *(float4*)&Wlds[k][q * 4];
            float4 a4 = *(float4*)&Alds[k][nb * 4];
            acc[0][0] += a4.x * w4.x; acc[0][1] += a4.x * w4.y;
            acc[0][2] += a4.x * w4.z; acc[0][3] += a4.x * w4.w;
            acc[1][0] += a4.y * w4.x; acc[1][1] += a4.y * w4.y;
            acc[1][2] += a4.y * w4.z; acc[1][3] += a4.y * w4.w;
            acc[2][0] += a4.z * w4.x; acc[2][1] += a4.z * w4.y;
            acc[2][2] += a4.z * w4.z; acc[2][3] += a4.z * w4.w;
            acc[3][0] += a4.w * w4.x; acc[3][1] += a4.w * w4.y;
            acc[3][2] += a4.w * w4.z; acc[3][3] += a4.w * w4.w;
        }
    }

    float4 bv = *(const float4*)(LB + q * 4);
    int nbase = n0 + nb * 4;
#pragma unroll
    for (int j = 0; j < 4; ++j) {
        int n = nbase + j;
        if (n < NNODES) {
            float4 r;
            r.x = acc[j][0] + bv.x;
            r.y = acc[j][1] + bv.y;
            r.z = acc[j][2] + bv.z;
            r.w = acc[j][3] + bv.w;
            *(float4*)(out + (size_t)n * LLDIM + q * 4) = r;
        }
    }
}

extern "C" void kernel_launch(void* const* d_in, const int* in_sizes, int n_in,
                              void* d_out, int out_size, void* d_ws, size_t ws_size,
                              hipStream_t stream) {
    const float* x     = (const float*)d_in[0];
    const int*   ei    = (const int*)d_in[1];
    const int*   et    = (const int*)d_in[2];
    const float* w1    = (const float*)d_in[3];
    const float* root1 = (const float*)d_in[4];
    const float* b1    = (const float*)d_in[5];
    const float* w2    = (const float*)d_in[6];
    const float* root2 = (const float*)d_in[7];
    const float* b2    = (const float*)d_in[8];
    const float* lin_w = (const float*)d_in[9];
    const float* lin_b = (const float*)d_in[10];

    float* bufA = (float*)d_ws;                      // N*96
    float* bufB = bufA + (size_t)NNODES * DIM;       // N*96
    float* agg  = bufB + (size_t)NNODES * DIM;       // N*96
    int* deg       = (int*)(agg + (size_t)NNODES * DIM);
    int* row_start = deg + SCAN_N;
    int* row_end   = row_start + SCAN_N;
    int* col       = row_end + SCAN_N;               // up to NEDGES
    int* partials  = col + NEDGES;                   // 256
    unsigned short* bt = (unsigned short*)(partials + 256);   // 3 * 2 * 96*192 ushorts

    const int edge_blocks = (NEDGES + 255) / 256;
    const int scan_blocks = (SCAN_N + 1023) / 1024;  // 147
    const int node_tiles  = (NNODES + 63) / 64;      // 782
    const int gath_blocks = (NNODES + 7) / 8;        // 6250

    // ---- weight prep (independent of everything else) ----
    prep_kernel<<<(3 * 96 * 192 + 255) / 256, 256, 0, stream>>>(w1, root1, w2, root2, bt);

    // ---- CSR build (edge structure is identical for all 3 layers) ----
    hipMemsetAsync(deg, 0, SCAN_N * sizeof(int), stream);
    hist_kernel<<<edge_blocks, 256, 0, stream>>>(ei, et, deg);
    scan1_kernel<<<scan_blocks, 256, 0, stream>>>(deg, row_start, partials, SCAN_N);
    scan2_kernel<<<1, 256, 0, stream>>>(partials, scan_blocks);
    scan3_kernel<<<(SCAN_N + 255) / 256, 256, 0, stream>>>(row_start, partials, SCAN_N);
    hipMemcpyAsync(row_end, row_start, SCAN_N * sizeof(int), hipMemcpyDeviceToDevice, stream);
    fill_kernel<<<edge_blocks, 256, 0, stream>>>(ei, et, row_end, col);

    // ---- Layer 0: rel 0, w1[0], root1, b1 :  x -> bufA ----
    gather_kernel<<<gath_blocks, 256, 0, stream>>>(x, row_start, row_end, col, agg, 0);
    layer_mfma_kernel<<<node_tiles, 256, 0, stream>>>(x, agg, bt + 0 * (size_t)BT_LAYER_STRIDE, b1, bufA);

    // ---- Layer 1: rel 1, w2[1], root2, b2 :  bufA -> bufB ----
    gather_kernel<<<gath_blocks, 256, 0, stream>>>(bufA, row_start, row_end, col, agg, 1);
    layer_mfma_kernel<<<node_tiles, 256, 0, stream>>>(bufA, agg, bt + 1 * (size_t)BT_LAYER_STRIDE, b2, bufB);

    // ---- Layer 2: rel 2, w2[2], root2, b2 :  bufB -> bufA ----
    gather_kernel<<<gath_blocks, 256, 0, stream>>>(bufB, row_start, row_end, col, agg, 2);
    layer_mfma_kernel<<<node_tiles, 256, 0, stream>>>(bufB, agg, bt + 2 * (size_t)BT_LAYER_STRIDE, b2, bufA);

    // ---- Final linear: bufA -> d_out ----
    final_kernel<<<node_tiles, 256, 0, stream>>>(bufA, lin_w, lin_b, (float*)d_out);
}

// Round 3
// 269.028 us; speedup vs baseline: 1.2965x; 1.0486x over previous
//
#include <hip/hip_runtime.h>

#define NNODES 50000
#define NEDGES 800000
#define DIM 96
#define LLDIM 64
#define NRELS 3            // metapath relations 0,1,2
#define SCAN_N (NRELS * NNODES)

// Frag-linear weight planes: per layer, hi plane then lo plane, 96*192 ushorts each.
// Element (c,k): ph=k/96, ks=(k%96)/32, g=(k%32)/8, kr=k%8, cg=c/16, r=c%16
// ushort offset = (((ph*3+ks)*6 + cg)*64 + g*16 + r)*8 + kr
#define BT_PLANE 18432                 // 96*192
#define BT_LAYER (2 * BT_PLANE)
#define BTL_PLANE 6144                 // 64*96 (final linear)
#define BT_LIN_OFF (3 * BT_LAYER)
#define BT_TOTAL (3 * BT_LAYER + 2 * BTL_PLANE)

typedef __attribute__((ext_vector_type(8))) short bf16x8;
typedef __attribute__((ext_vector_type(4))) float f32x4;

__device__ __forceinline__ unsigned short f2bf(float x) {
    union { float f; unsigned u; } v; v.f = x;
    unsigned r = v.u + 0x7fffu + ((v.u >> 16) & 1u);   // round-to-nearest-even
    return (unsigned short)(r >> 16);
}
__device__ __forceinline__ float bf2f(unsigned short b) {
    union { unsigned u; float f; } v; v.u = ((unsigned)b) << 16;
    return v.f;
}

// ---------------- CSR build ----------------

__global__ void hist_kernel(const int* __restrict__ ei, const int* __restrict__ et,
                            int* __restrict__ deg) {
    int e = blockIdx.x * 256 + threadIdx.x;
    if (e >= NEDGES) return;
    int r = et[e];
    if (r < NRELS) atomicAdd(&deg[r * NNODES + ei[e]], 1);
}

__global__ void scan1_kernel(const int* __restrict__ in, int* __restrict__ out,
                             int* __restrict__ partials, int n) {
    __shared__ int sdata[256];
    int tid = threadIdx.x;
    int base = blockIdx.x * 1024 + tid * 4;
    int v0 = (base + 0 < n) ? in[base + 0] : 0;
    int v1 = (base + 1 < n) ? in[base + 1] : 0;
    int v2 = (base + 2 < n) ? in[base + 2] : 0;
    int v3 = (base + 3 < n) ? in[base + 3] : 0;
    int tsum = v0 + v1 + v2 + v3;
    sdata[tid] = tsum;
    __syncthreads();
    for (int off = 1; off < 256; off <<= 1) {
        int x = sdata[tid];
        int y = (tid >= off) ? sdata[tid - off] : 0;
        __syncthreads();
        sdata[tid] = x + y;
        __syncthreads();
    }
    int excl = sdata[tid] - tsum;
    if (tid == 255) partials[blockIdx.x] = sdata[255];
    if (base + 0 < n) out[base + 0] = excl;
    excl += v0;
    if (base + 1 < n) out[base + 1] = excl;
    excl += v1;
    if (base + 2 < n) out[base + 2] = excl;
    excl += v2;
    if (base + 3 < n) out[base + 3] = excl;
}

__global__ void scan2_kernel(int* __restrict__ partials, int nb) {
    __shared__ int sdata[256];
    int tid = threadIdx.x;
    int v = (tid < nb) ? partials[tid] : 0;
    sdata[tid] = v;
    __syncthreads();
    for (int off = 1; off < 256; off <<= 1) {
        int x = sdata[tid];
        int y = (tid >= off) ? sdata[tid - off] : 0;
        __syncthreads();
        sdata[tid] = x + y;
        __syncthreads();
    }
    partials[tid] = sdata[tid] - v;   // exclusive
}

__global__ void scan3_kernel(int* __restrict__ out, const int* __restrict__ partials, int n) {
    int idx = blockIdx.x * 256 + threadIdx.x;
    if (idx < n) out[idx] += partials[idx >> 10];
}

__global__ void fill_kernel(const int* __restrict__ ei, const int* __restrict__ et,
                            int* __restrict__ cursor, int* __restrict__ col) {
    int e = blockIdx.x * 256 + threadIdx.x;
    if (e >= NEDGES) return;
    int r = et[e];
    if (r < NRELS) {
        int pos = atomicAdd(&cursor[r * NNODES + ei[e]], 1);
        col[pos] = ei[NEDGES + e];
    }
}

// ---------------- per-layer aggregate (gather, mean folded in) ----------------
// 2-way unrolled: two independent col->row dependent-load chains in flight.

__global__ void gather_kernel(const float* __restrict__ h, const int* __restrict__ row_start,
                              const int* __restrict__ row_end, const int* __restrict__ col,
                              float* __restrict__ agg, int rel) {
    int g = blockIdx.x * 8 + (threadIdx.x >> 5);   // node id
    if (g >= NNODES) return;
    int lane = threadIdx.x & 31;
    int s = row_start[rel * NNODES + g];
    int e = row_end[rel * NNODES + g];
    float a0 = 0.0f, a1 = 0.0f, a2 = 0.0f;
    float b0 = 0.0f, b1 = 0.0f, b2 = 0.0f;
    int i = s;
    for (; i + 2 <= e; i += 2) {
        int d0 = col[i];
        int d1 = col[i + 1];
        const float* p0 = h + (size_t)d0 * DIM;
        const float* p1 = h + (size_t)d1 * DIM;
        float x0 = p0[lane], x1 = p0[lane + 32], x2 = p0[lane + 64];
        float y0 = p1[lane], y1 = p1[lane + 32], y2 = p1[lane + 64];
        a0 += x0; a1 += x1; a2 += x2;
        b0 += y0; b1 += y1; b2 += y2;
    }
    if (i < e) {
        int d = col[i];
        const float* p = h + (size_t)d * DIM;
        a0 += p[lane]; a1 += p[lane + 32]; a2 += p[lane + 64];
    }
    a0 += b0; a1 += b1; a2 += b2;
    float scl = 1.0f / fmaxf((float)(e - s), 1.0f);
    float* ar = agg + (size_t)g * DIM;
    ar[lane] = a0 * scl;
    ar[lane + 32] = a1 * scl;
    ar[lane + 64] = a2 * scl;
}

// ---------------- weight prep: frag-linear bf16 hi/lo planes ----------------
// Layers: Bcat_l = [W_l ; R_l] (192 x 96), split hi/lo, frag-linear (see top).
// Final:  lin_w (96 x 64), same scheme with ph=0 only, 4 col-groups.

__global__ void prep_kernel(const float* __restrict__ w1, const float* __restrict__ root1,
                            const float* __restrict__ w2, const float* __restrict__ root2,
                            const float* __restrict__ lin_w,
                            unsigned short* __restrict__ bt) {
    int idx = blockIdx.x * 256 + threadIdx.x;
    const int LYR = 96 * 192;
    if (idx < 3 * LYR) {
        int l = idx / LYR;
        int rem = idx % LYR;
        int c = rem / 192;
        int k = rem % 192;
        const float* Wm;
        const float* Rm;
        if (l == 0) { Wm = w1; Rm = root1; }
        else        { Wm = w2 + (size_t)l * 96 * 96; Rm = root2; }
        float v = (k < 96) ? Wm[(size_t)k * 96 + c] : Rm[(size_t)(k - 96) * 96 + c];
        unsigned short hi = f2bf(v);
        unsigned short lo = f2bf(v - bf2f(hi));
        int ph = k / 96, kk = k % 96;
        int ks = kk / 32, g = (kk & 31) >> 3, kr = k & 7;
        int cg = c >> 4, r = c & 15;
        size_t off = (((size_t)((ph * 3 + ks) * 6 + cg)) * 64 + g * 16 + r) * 8 + kr;
        unsigned short* base = bt + (size_t)l * BT_LAYER;
        base[off] = hi;
        base[BT_PLANE + off] = lo;
    } else if (idx < 3 * LYR + 64 * 96) {
        int rem = idx - 3 * LYR;
        int c = rem / 96;
        int k = rem % 96;
        float v = lin_w[(size_t)k * 64 + c];
        unsigned short hi = f2bf(v);
        unsigned short lo = f2bf(v - bf2f(hi));
        int ks = k / 32, g = (k & 31) >> 3, kr = k & 7;
        int cg = c >> 4, r = c & 15;
        size_t off = (((size_t)(ks * 4 + cg)) * 64 + g * 16 + r) * 8 + kr;
        unsigned short* base = bt + BT_LIN_OFF;
        base[off] = hi;
        base[BTL_PLANE + off] = lo;
    }
}

// ---------------- layer GEMM via split-bf16 MFMA, B global->reg ----------------
// out = relu([agg|h] @ [W;R] + b), K=192 in 2 phases. Block 256 thr (4 waves),
// tile 64 nodes x 96 cols; wave = 32 rows x 48 cols. A staged hi/lo in LDS
// (26.6 KB -> ~5 blocks/CU); B frags loaded per-lane from frag-linear global
// planes (L1/L2-resident, coalesced 1 KB/wave/inst) -> LDS pipe only carries A.

__global__ __launch_bounds__(256) void layer_mfma_kernel(
    const float* __restrict__ h, const float* __restrict__ agg,
    const unsigned short* __restrict__ bt,   // layer base (hi; lo at +BT_PLANE)
    const float* __restrict__ b, float* __restrict__ out) {
    __shared__ unsigned short Ah[64 * 104];
    __shared__ unsigned short Al[64 * 104];
    const int tid = threadIdx.x;
    const int lane = tid & 63;
    const int w = tid >> 6;                 // 0..3
    const int r = lane & 15;
    const int g = lane >> 4;                // 0..3
    const int rb_base = (w >> 1) * 32;      // 0 or 32
    const int cg_base = (w & 1) * 3;        // col-group base (16-col groups)
    const int n0 = blockIdx.x * 64;

    f32x4 acc[2][3];
#pragma unroll
    for (int i = 0; i < 2; ++i)
#pragma unroll
        for (int j = 0; j < 3; ++j) acc[i][j] = (f32x4){0.f, 0.f, 0.f, 0.f};

    for (int ph = 0; ph < 2; ++ph) {
        const float* src = ph ? h : agg;
        __syncthreads();                      // previous phase done reading LDS
        // stage A (64x96 fp32 -> hi/lo bf16, [node][k], rows padded to 104)
#pragma unroll
        for (int j = 0; j < 6; ++j) {
            int idx = tid + j * 256;          // 0..1535 float4s
            int nd = idx / 24;
            int kq = idx % 24;
            int node = n0 + nd;
            if (node >= NNODES) node = NNODES - 1;   // stores guarded later
            float4 v = *(const float4*)(src + (size_t)node * DIM + kq * 4);
            unsigned short h0 = f2bf(v.x), h1 = f2bf(v.y), h2 = f2bf(v.z), h3 = f2bf(v.w);
            *(ushort4*)&Ah[nd * 104 + kq * 4] = make_ushort4(h0, h1, h2, h3);
            unsigned short l0 = f2bf(v.x - bf2f(h0));
            unsigned short l1 = f2bf(v.y - bf2f(h1));
            unsigned short l2 = f2bf(v.z - bf2f(h2));
            unsigned short l3 = f2bf(v.w - bf2f(h3));
            *(ushort4*)&Al[nd * 104 + kq * 4] = make_ushort4(l0, l1, l2, l3);
        }
        __syncthreads();
#pragma unroll
        for (int ks = 0; ks < 3; ++ks) {
            const int ko = ks * 32 + g * 8;
            bf16x8 a0h = *(const bf16x8*)&Ah[(rb_base + r) * 104 + ko];
            bf16x8 a1h = *(const bf16x8*)&Ah[(rb_base + 16 + r) * 104 + ko];
            bf16x8 a0l = *(const bf16x8*)&Al[(rb_base + r) * 104 + ko];
            bf16x8 a1l = *(const bf16x8*)&Al[(rb_base + 16 + r) * 104 + ko];
            // B frag base for this (ph,ks): frag f = ((ph*3+ks)*6 + cg)*64 + lane
            const unsigned short* bks =
                bt + ((size_t)((ph * 3 + ks) * 6) * 64 + lane) * 8;
#pragma unroll
            for (int ct = 0; ct < 3; ++ct) {
                const unsigned short* bp = bks + (size_t)(cg_base + ct) * 512;
                bf16x8 bhv = *(const bf16x8*)bp;
                bf16x8 blv = *(const bf16x8*)(bp + BT_PLANE);
                acc[0][ct] = __builtin_amdgcn_mfma_f32_16x16x32_bf16(a0h, bhv, acc[0][ct], 0, 0, 0);
                acc[1][ct] = __builtin_amdgcn_mfma_f32_16x16x32_bf16(a1h, bhv, acc[1][ct], 0, 0, 0);
                acc[0][ct] = __builtin_amdgcn_mfma_f32_16x16x32_bf16(a0l, bhv, acc[0][ct], 0, 0, 0);
                acc[1][ct] = __builtin_amdgcn_mfma_f32_16x16x32_bf16(a1l, bhv, acc[1][ct], 0, 0, 0);
                acc[0][ct] = __builtin_amdgcn_mfma_f32_16x16x32_bf16(a0h, blv, acc[0][ct], 0, 0, 0);
                acc[1][ct] = __builtin_amdgcn_mfma_f32_16x16x32_bf16(a1h, blv, acc[1][ct], 0, 0, 0);
            }
        }
    }

    // epilogue: C/D layout: col = lane&15, row = g*4 + j (HW-verified, passed R2)
#pragma unroll
    for (int ct = 0; ct < 3; ++ct) {
        int colc = (cg_base + ct) * 16 + r;
        float bias = b[colc];
#pragma unroll
        for (int rbi = 0; rbi < 2; ++rbi) {
            int row0 = n0 + rb_base + rbi * 16 + g * 4;
#pragma unroll
            for (int j = 0; j < 4; ++j) {
                int node = row0 + j;
                if (node < NNODES)
                    out[(size_t)node * DIM + colc] = fmaxf(acc[rbi][ct][j] + bias, 0.0f);
            }
        }
    }
}

// ---------------- final linear via split-bf16 MFMA (no relu) ----------------
// tile 64 nodes x 64 cols, 4 waves: wave = 32 rows x 32 cols, K=96.

__global__ __launch_bounds__(256) void final_mfma_kernel(
    const float* __restrict__ h, const unsigned short* __restrict__ btl,
    const float* __restrict__ LB, float* __restrict__ out) {
    __shared__ unsigned short Ah[64 * 104];
    __shared__ unsigned short Al[64 * 104];
    const int tid = threadIdx.x;
    const int lane = tid & 63;
    const int w = tid >> 6;
    const int r = lane & 15;
    const int g = lane >> 4;
    const int rb_base = (w >> 1) * 32;
    const int cg_base = (w & 1) * 2;        // 2 col-groups per wave (32 cols)
    const int n0 = blockIdx.x * 64;

    f32x4 acc[2][2];
#pragma unroll
    for (int i = 0; i < 2; ++i)
#pragma unroll
        for (int j = 0; j < 2; ++j) acc[i][j] = (f32x4){0.f, 0.f, 0.f, 0.f};

#pragma unroll
    for (int j = 0; j < 6; ++j) {
        int idx = tid + j * 256;
        int nd = idx / 24;
        int kq = idx % 24;
        int node = n0 + nd;
        if (node >= NNODES) node = NNODES - 1;
        float4 v = *(const float4*)(h + (size_t)node * DIM + kq * 4);
        unsigned short h0 = f2bf(v.x), h1 = f2bf(v.y), h2 = f2bf(v.z), h3 = f2bf(v.w);
        *(ushort4*)&Ah[nd * 104 + kq * 4] = make_ushort4(h0, h1, h2, h3);
        unsigned short l0 = f2bf(v.x - bf2f(h0));
        unsigned short l1 = f2bf(v.y - bf2f(h1));
        unsigned short l2 = f2bf(v.z - bf2f(h2));
        unsigned short l3 = f2bf(v.w - bf2f(h3));
        *(ushort4*)&Al[nd * 104 + kq * 4] = make_ushort4(l0, l1, l2, l3);
    }
    __syncthreads();
#pragma unroll
    for (int ks = 0; ks < 3; ++ks) {
        const int ko = ks * 32 + g * 8;
        bf16x8 a0h = *(const bf16x8*)&Ah[(rb_base + r) * 104 + ko];
        bf16x8 a1h = *(const bf16x8*)&Ah[(rb_base + 16 + r) * 104 + ko];
        bf16x8 a0l = *(const bf16x8*)&Al[(rb_base + r) * 104 + ko];
        bf16x8 a1l = *(const bf16x8*)&Al[(rb_base + 16 + r) * 104 + ko];
        const unsigned short* bks = btl + ((size_t)(ks * 4) * 64 + lane) * 8;
#pragma unroll
        for (int ct = 0; ct < 2; ++ct) {
            const unsigned short* bp = bks + (size_t)(cg_base + ct) * 512;
            bf16x8 bhv = *(const bf16x8*)bp;
            bf16x8 blv = *(const bf16x8*)(bp + BTL_PLANE);
            acc[0][ct] = __builtin_amdgcn_mfma_f32_16x16x32_bf16(a0h, bhv, acc[0][ct], 0, 0, 0);
            acc[1][ct] = __builtin_amdgcn_mfma_f32_16x16x32_bf16(a1h, bhv, acc[1][ct], 0, 0, 0);
            acc[0][ct] = __builtin_amdgcn_mfma_f32_16x16x32_bf16(a0l, bhv, acc[0][ct], 0, 0, 0);
            acc[1][ct] = __builtin_amdgcn_mfma_f32_16x16x32_bf16(a1l, bhv, acc[1][ct], 0, 0, 0);
            acc[0][ct] = __builtin_amdgcn_mfma_f32_16x16x32_bf16(a0h, blv, acc[0][ct], 0, 0, 0);
            acc[1][ct] = __builtin_amdgcn_mfma_f32_16x16x32_bf16(a1h, blv, acc[1][ct], 0, 0, 0);
        }
    }

#pragma unroll
    for (int ct = 0; ct < 2; ++ct) {
        int colc = (cg_base + ct) * 16 + r;
        float bias = LB[colc];
#pragma unroll
        for (int rbi = 0; rbi < 2; ++rbi) {
            int row0 = n0 + rb_base + rbi * 16 + g * 4;
#pragma unroll
            for (int j = 0; j < 4; ++j) {
                int node = row0 + j;
                if (node < NNODES)
                    out[(size_t)node * LLDIM + colc] = acc[rbi][ct][j] + bias;
            }
        }
    }
}

extern "C" void kernel_launch(void* const* d_in, const int* in_sizes, int n_in,
                              void* d_out, int out_size, void* d_ws, size_t ws_size,
                              hipStream_t stream) {
    const float* x     = (const float*)d_in[0];
    const int*   ei    = (const int*)d_in[1];
    const int*   et    = (const int*)d_in[2];
    const float* w1    = (const float*)d_in[3];
    const float* root1 = (const float*)d_in[4];
    const float* b1    = (const float*)d_in[5];
    const float* w2    = (const float*)d_in[6];
    const float* root2 = (const float*)d_in[7];
    const float* b2    = (const float*)d_in[8];
    const float* lin_w = (const float*)d_in[9];
    const float* lin_b = (const float*)d_in[10];

    float* bufA = (float*)d_ws;                      // N*96
    float* bufB = bufA + (size_t)NNODES * DIM;       // N*96
    float* agg  = bufB + (size_t)NNODES * DIM;       // N*96
    int* deg       = (int*)(agg + (size_t)NNODES * DIM);
    int* row_start = deg + SCAN_N;
    int* row_end   = row_start + SCAN_N;
    int* col       = row_end + SCAN_N;               // up to NEDGES
    int* partials  = col + NEDGES;                   // 256
    unsigned short* bt = (unsigned short*)(partials + 256);   // BT_TOTAL ushorts

    const int edge_blocks = (NEDGES + 255) / 256;
    const int scan_blocks = (SCAN_N + 1023) / 1024;  // 147
    const int node_tiles  = (NNODES + 63) / 64;      // 782
    const int gath_blocks = (NNODES + 7) / 8;        // 6250
    const int prep_items  = 3 * 96 * 192 + 64 * 96;  // 61440

    // ---- weight prep (independent of everything else) ----
    prep_kernel<<<(prep_items + 255) / 256, 256, 0, stream>>>(w1, root1, w2, root2, lin_w, bt);

    // ---- CSR build (edge structure is identical for all 3 layers) ----
    hipMemsetAsync(deg, 0, SCAN_N * sizeof(int), stream);
    hist_kernel<<<edge_blocks, 256, 0, stream>>>(ei, et, deg);
    scan1_kernel<<<scan_blocks, 256, 0, stream>>>(deg, row_start, partials, SCAN_N);
    scan2_kernel<<<1, 256, 0, stream>>>(partials, scan_blocks);
    scan3_kernel<<<(SCAN_N + 255) / 256, 256, 0, stream>>>(row_start, partials, SCAN_N);
    hipMemcpyAsync(row_end, row_start, SCAN_N * sizeof(int), hipMemcpyDeviceToDevice, stream);
    fill_kernel<<<edge_blocks, 256, 0, stream>>>(ei, et, row_end, col);

    // ---- Layer 0: rel 0, w1[0], root1, b1 :  x -> bufA ----
    gather_kernel<<<gath_blocks, 256, 0, stream>>>(x, row_start, row_end, col, agg, 0);
    layer_mfma_kernel<<<node_tiles, 256, 0, stream>>>(x, agg, bt + 0 * (size_t)BT_LAYER, b1, bufA);

    // ---- Layer 1: rel 1, w2[1], root2, b2 :  bufA -> bufB ----
    gather_kernel<<<gath_blocks, 256, 0, stream>>>(bufA, row_start, row_end, col, agg, 1);
    layer_mfma_kernel<<<node_tiles, 256, 0, stream>>>(bufA, agg, bt + 1 * (size_t)BT_LAYER, b2, bufB);

    // ---- Layer 2: rel 2, w2[2], root2, b2 :  bufB -> bufA ----
    gather_kernel<<<gath_blocks, 256, 0, stream>>>(bufB, row_start, row_end, col, agg, 2);
    layer_mfma_kernel<<<node_tiles, 256, 0, stream>>>(bufB, agg, bt + 2 * (size_t)BT_LAYER, b2, bufA);

    // ---- Final linear: bufA -> d_out ----
    final_mfma_kernel<<<node_tiles, 256, 0, stream>>>(bufA, bt + BT_LIN_OFF, lin_b, (float*)d_out);
}

// Round 4
// 221.312 us; speedup vs baseline: 1.5761x; 1.2156x over previous
//
#include <hip/hip_runtime.h>

#define NNODES 50000
#define NEDGES 800000
#define DIM 96
#define LLDIM 64
#define NRELS 3            // metapath relations 0,1,2
#define SCAN_N (NRELS * NNODES)

// Frag-linear weight planes: per layer, hi plane then lo plane, 96*192 ushorts each.
// Element (c,k): ph=k/96, ks=(k%96)/32, g=(k%32)/8, kr=k%8, cg=c/16, r=c%16
// ushort offset = (((ph*3+ks)*6 + cg)*64 + g*16 + r)*8 + kr
#define BT_PLANE 18432                 // 96*192
#define BT_LAYER (2 * BT_PLANE)
#define BTL_PLANE 6144                 // 64*96 (final linear)
#define BT_LIN_OFF (3 * BT_LAYER)

typedef __attribute__((ext_vector_type(8))) short bf16x8;
typedef __attribute__((ext_vector_type(4))) float f32x4;

__device__ __forceinline__ unsigned short f2bf(float x) {
    union { float f; unsigned u; } v; v.f = x;
    unsigned r = v.u + 0x7fffu + ((v.u >> 16) & 1u);   // round-to-nearest-even
    return (unsigned short)(r >> 16);
}
__device__ __forceinline__ float bf2f(unsigned short b) {
    union { unsigned u; float f; } v; v.u = ((unsigned)b) << 16;
    return v.f;
}

// ---------------- CSR build ----------------

__global__ void hist_kernel(const int* __restrict__ ei, const int* __restrict__ et,
                            int* __restrict__ deg) {
    int e = blockIdx.x * 256 + threadIdx.x;
    if (e >= NEDGES) return;
    int r = et[e];
    if (r < NRELS) atomicAdd(&deg[r * NNODES + ei[e]], 1);
}

__global__ void scan1_kernel(const int* __restrict__ in, int* __restrict__ out,
                             int* __restrict__ partials, int n) {
    __shared__ int sdata[256];
    int tid = threadIdx.x;
    int base = blockIdx.x * 1024 + tid * 4;
    int v0 = (base + 0 < n) ? in[base + 0] : 0;
    int v1 = (base + 1 < n) ? in[base + 1] : 0;
    int v2 = (base + 2 < n) ? in[base + 2] : 0;
    int v3 = (base + 3 < n) ? in[base + 3] : 0;
    int tsum = v0 + v1 + v2 + v3;
    sdata[tid] = tsum;
    __syncthreads();
    for (int off = 1; off < 256; off <<= 1) {
        int x = sdata[tid];
        int y = (tid >= off) ? sdata[tid - off] : 0;
        __syncthreads();
        sdata[tid] = x + y;
        __syncthreads();
    }
    int excl = sdata[tid] - tsum;
    if (tid == 255) partials[blockIdx.x] = sdata[255];
    if (base + 0 < n) out[base + 0] = excl;
    excl += v0;
    if (base + 1 < n) out[base + 1] = excl;
    excl += v1;
    if (base + 2 < n) out[base + 2] = excl;
    excl += v2;
    if (base + 3 < n) out[base + 3] = excl;
}

__global__ void scan2_kernel(int* __restrict__ partials, int nb) {
    __shared__ int sdata[256];
    int tid = threadIdx.x;
    int v = (tid < nb) ? partials[tid] : 0;
    sdata[tid] = v;
    __syncthreads();
    for (int off = 1; off < 256; off <<= 1) {
        int x = sdata[tid];
        int y = (tid >= off) ? sdata[tid - off] : 0;
        __syncthreads();
        sdata[tid] = x + y;
        __syncthreads();
    }
    partials[tid] = sdata[tid] - v;   // exclusive
}

// adds block offsets AND initializes the fill cursor (row_end) = row_start.
__global__ void scan3_kernel(int* __restrict__ out, int* __restrict__ cursor,
                             const int* __restrict__ partials, int n) {
    int idx = blockIdx.x * 256 + threadIdx.x;
    if (idx < n) {
        int v = out[idx] + partials[idx >> 10];
        out[idx] = v;
        cursor[idx] = v;
    }
}

__global__ void fill_kernel(const int* __restrict__ ei, const int* __restrict__ et,
                            int* __restrict__ cursor, int* __restrict__ col) {
    int e = blockIdx.x * 256 + threadIdx.x;
    if (e >= NEDGES) return;
    int r = et[e];
    if (r < NRELS) {
        int pos = atomicAdd(&cursor[r * NNODES + ei[e]], 1);
        col[pos] = ei[NEDGES + e];
    }
}

// ---------------- weight prep (+ deg zeroing, saves a memset dispatch) ----------------

__global__ void prep_kernel(const float* __restrict__ w1, const float* __restrict__ root1,
                            const float* __restrict__ w2, const float* __restrict__ root2,
                            const float* __restrict__ lin_w,
                            unsigned short* __restrict__ bt, int* __restrict__ deg) {
    int idx = blockIdx.x * 256 + threadIdx.x;
    if (idx < SCAN_N) deg[idx] = 0;
    const int LYR = 96 * 192;
    if (idx < 3 * LYR) {
        int l = idx / LYR;
        int rem = idx % LYR;
        int c = rem / 192;
        int k = rem % 192;
        const float* Wm;
        const float* Rm;
        if (l == 0) { Wm = w1; Rm = root1; }
        else        { Wm = w2 + (size_t)l * 96 * 96; Rm = root2; }
        float v = (k < 96) ? Wm[(size_t)k * 96 + c] : Rm[(size_t)(k - 96) * 96 + c];
        unsigned short hi = f2bf(v);
        unsigned short lo = f2bf(v - bf2f(hi));
        int ph = k / 96, kk = k % 96;
        int ks = kk / 32, g = (kk & 31) >> 3, kr = k & 7;
        int cg = c >> 4, r = c & 15;
        size_t off = (((size_t)((ph * 3 + ks) * 6 + cg)) * 64 + g * 16 + r) * 8 + kr;
        unsigned short* base = bt + (size_t)l * BT_LAYER;
        base[off] = hi;
        base[BT_PLANE + off] = lo;
    } else if (idx < 3 * LYR + 64 * 96) {
        int rem = idx - 3 * LYR;
        int c = rem / 96;
        int k = rem % 96;
        float v = lin_w[(size_t)k * 64 + c];
        unsigned short hi = f2bf(v);
        unsigned short lo = f2bf(v - bf2f(hi));
        int ks = k / 32, g = (k & 31) >> 3, kr = k & 7;
        int cg = c >> 4, r = c & 15;
        size_t off = (((size_t)(ks * 4 + cg)) * 64 + g * 16 + r) * 8 + kr;
        unsigned short* base = bt + BT_LIN_OFF;
        base[off] = hi;
        base[BTL_PLANE + off] = lo;
    }
}

// ---------------- fused gather + layer GEMM ----------------
// out = relu([mean_gather(h)|h] @ [W;R] + b). Block 256 thr (4 waves), 64 nodes.
// Gather: 4 thr/node, each owns 24 cols; per neighbor 6 float4 loads (16
// independent node-streams per wave -> deep MLP). Result converted to bf16
// hi/lo straight into LDS (no agg buffer). Then 2-phase MFMA as before.
// Wave w: rows rb_base..+32, cols cg_base*16..+48.

__device__ __forceinline__ void gather_to_lds(
    const float* __restrict__ h, const int* __restrict__ rs, const int* __restrict__ re,
    const int* __restrict__ col, int n0, int tid,
    unsigned short* Ah, unsigned short* Al) {
    const int nd = tid >> 2;               // 0..63
    const int node = n0 + nd;
    const int cq4 = (tid & 3) * 24;        // col base (24 cols per thread)
    float a[24];
#pragma unroll
    for (int j = 0; j < 24; ++j) a[j] = 0.0f;
    int s = 0, e = 0;
    if (node < NNODES) { s = rs[node]; e = re[node]; }
    for (int i = s; i < e; ++i) {
        int d = col[i];
        const float* p = h + (size_t)d * DIM + cq4;
#pragma unroll
        for (int j6 = 0; j6 < 6; ++j6) {
            float4 v = *(const float4*)(p + j6 * 4);
            a[j6 * 4 + 0] += v.x; a[j6 * 4 + 1] += v.y;
            a[j6 * 4 + 2] += v.z; a[j6 * 4 + 3] += v.w;
        }
    }
    float scl = 1.0f / fmaxf((float)(e - s), 1.0f);
    int arow = nd * 104 + cq4;
#pragma unroll
    for (int jp = 0; jp < 12; ++jp) {
        float v0 = a[jp * 2] * scl, v1 = a[jp * 2 + 1] * scl;
        unsigned short h0 = f2bf(v0), h1 = f2bf(v1);
        unsigned short l0 = f2bf(v0 - bf2f(h0)), l1 = f2bf(v1 - bf2f(h1));
        *(unsigned int*)&Ah[arow + jp * 2] = (unsigned)h0 | ((unsigned)h1 << 16);
        *(unsigned int*)&Al[arow + jp * 2] = (unsigned)l0 | ((unsigned)l1 << 16);
    }
}

__device__ __forceinline__ void stage_h_to_lds(
    const float* __restrict__ src, int n0, int tid,
    unsigned short* Ah, unsigned short* Al) {
#pragma unroll
    for (int j = 0; j < 6; ++j) {
        int idx = tid + j * 256;           // 0..1535 float4s
        int nd = idx / 24;
        int kq = idx % 24;
        int node = n0 + nd;
        if (node >= NNODES) node = NNODES - 1;   // results discarded on store guard
        float4 v = *(const float4*)(src + (size_t)node * DIM + kq * 4);
        unsigned short h0 = f2bf(v.x), h1 = f2bf(v.y), h2 = f2bf(v.z), h3 = f2bf(v.w);
        *(ushort4*)&Ah[nd * 104 + kq * 4] = make_ushort4(h0, h1, h2, h3);
        unsigned short l0 = f2bf(v.x - bf2f(h0));
        unsigned short l1 = f2bf(v.y - bf2f(h1));
        unsigned short l2 = f2bf(v.z - bf2f(h2));
        unsigned short l3 = f2bf(v.w - bf2f(h3));
        *(ushort4*)&Al[nd * 104 + kq * 4] = make_ushort4(l0, l1, l2, l3);
    }
}

#define KS_LOOP(PH)                                                                     \
    _Pragma("unroll")                                                                   \
    for (int ks = 0; ks < 3; ++ks) {                                                    \
        const int ko = ks * 32 + g * 8;                                                 \
        bf16x8 a0h = *(const bf16x8*)&Ah[(rb_base + r) * 104 + ko];                     \
        bf16x8 a1h = *(const bf16x8*)&Ah[(rb_base + 16 + r) * 104 + ko];                \
        bf16x8 a0l = *(const bf16x8*)&Al[(rb_base + r) * 104 + ko];                     \
        bf16x8 a1l = *(const bf16x8*)&Al[(rb_base + 16 + r) * 104 + ko];                \
        const unsigned short* bks = bt + ((size_t)(((PH) * 3 + ks) * 6) * 64 + lane) * 8;\
        _Pragma("unroll")                                                               \
        for (int ct = 0; ct < 3; ++ct) {                                                \
            const unsigned short* bp = bks + (size_t)(cg_base + ct) * 512;              \
            bf16x8 bhv = *(const bf16x8*)bp;                                            \
            bf16x8 blv = *(const bf16x8*)(bp + BT_PLANE);                               \
            acc[0][ct] = __builtin_amdgcn_mfma_f32_16x16x32_bf16(a0h, bhv, acc[0][ct], 0, 0, 0); \
            acc[1][ct] = __builtin_amdgcn_mfma_f32_16x16x32_bf16(a1h, bhv, acc[1][ct], 0, 0, 0); \
            acc[0][ct] = __builtin_amdgcn_mfma_f32_16x16x32_bf16(a0l, bhv, acc[0][ct], 0, 0, 0); \
            acc[1][ct] = __builtin_amdgcn_mfma_f32_16x16x32_bf16(a1l, bhv, acc[1][ct], 0, 0, 0); \
            acc[0][ct] = __builtin_amdgcn_mfma_f32_16x16x32_bf16(a0h, blv, acc[0][ct], 0, 0, 0); \
            acc[1][ct] = __builtin_amdgcn_mfma_f32_16x16x32_bf16(a1h, blv, acc[1][ct], 0, 0, 0); \
        }                                                                               \
    }

__global__ __launch_bounds__(256) void layer_fused_kernel(
    const float* __restrict__ h, const int* __restrict__ rs, const int* __restrict__ re,
    const int* __restrict__ col, const unsigned short* __restrict__ bt,
    const float* __restrict__ b, float* __restrict__ out) {
    __shared__ unsigned short Ah[64 * 104];
    __shared__ unsigned short Al[64 * 104];
    const int tid = threadIdx.x;
    const int lane = tid & 63;
    const int w = tid >> 6;
    const int r = lane & 15;
    const int g = lane >> 4;
    const int rb_base = (w >> 1) * 32;
    const int cg_base = (w & 1) * 3;
    const int n0 = blockIdx.x * 64;

    // phase 0 A-operand: gathered neighbor mean, straight to LDS
    gather_to_lds(h, rs, re, col, n0, tid, Ah, Al);

    f32x4 acc[2][3];
#pragma unroll
    for (int i = 0; i < 2; ++i)
#pragma unroll
        for (int j = 0; j < 3; ++j) acc[i][j] = (f32x4){0.f, 0.f, 0.f, 0.f};

    __syncthreads();
    KS_LOOP(0)
    __syncthreads();                       // done reading phase-0 A
    stage_h_to_lds(h, n0, tid, Ah, Al);    // phase 1 A-operand: h tile
    __syncthreads();
    KS_LOOP(1)

    // epilogue: C/D layout: col = lane&15, row = g*4 + j
#pragma unroll
    for (int ct = 0; ct < 3; ++ct) {
        int colc = (cg_base + ct) * 16 + r;
        float bias = b[colc];
#pragma unroll
        for (int rbi = 0; rbi < 2; ++rbi) {
            int row0 = n0 + rb_base + rbi * 16 + g * 4;
#pragma unroll
            for (int j = 0; j < 4; ++j) {
                int node = row0 + j;
                if (node < NNODES)
                    out[(size_t)node * DIM + colc] = fmaxf(acc[rbi][ct][j] + bias, 0.0f);
            }
        }
    }
}

// ---------------- fused gather + layer 2 + final linear ----------------
// Same as layer_fused, but h2 = relu(acc+bias) goes to LDS (bf16 hi/lo) and the
// final GEMM (K=96, 64 cols, + lin_b, no relu) runs in-block -> writes d_out.

__global__ __launch_bounds__(256) void layer2_final_kernel(
    const float* __restrict__ h, const int* __restrict__ rs, const int* __restrict__ re,
    const int* __restrict__ col, const unsigned short* __restrict__ bt,
    const float* __restrict__ b, const unsigned short* __restrict__ btl,
    const float* __restrict__ LB, float* __restrict__ out) {
    __shared__ unsigned short Ah[64 * 104];
    __shared__ unsigned short Al[64 * 104];
    const int tid = threadIdx.x;
    const int lane = tid & 63;
    const int w = tid >> 6;
    const int r = lane & 15;
    const int g = lane >> 4;
    const int rb_base = (w >> 1) * 32;
    const int cg_base = (w & 1) * 3;
    const int n0 = blockIdx.x * 64;

    gather_to_lds(h, rs, re, col, n0, tid, Ah, Al);

    f32x4 acc[2][3];
#pragma unroll
    for (int i = 0; i < 2; ++i)
#pragma unroll
        for (int j = 0; j < 3; ++j) acc[i][j] = (f32x4){0.f, 0.f, 0.f, 0.f};

    __syncthreads();
    KS_LOOP(0)
    __syncthreads();
    stage_h_to_lds(h, n0, tid, Ah, Al);
    __syncthreads();
    KS_LOOP(1)

    // h2 = relu(acc+bias) -> LDS bf16 hi/lo, layout [row][k]
    __syncthreads();                       // all waves done reading phase-1 A
#pragma unroll
    for (int ct = 0; ct < 3; ++ct) {
        int colc = (cg_base + ct) * 16 + r;
        float bias = b[colc];
#pragma unroll
        for (int rbi = 0; rbi < 2; ++rbi) {
            int row0 = rb_base + rbi * 16 + g * 4;
#pragma unroll
            for (int j = 0; j < 4; ++j) {
                float v = fmaxf(acc[rbi][ct][j] + bias, 0.0f);
                unsigned short hh = f2bf(v);
                unsigned short ll = f2bf(v - bf2f(hh));
                Ah[(row0 + j) * 104 + colc] = hh;
                Al[(row0 + j) * 104 + colc] = ll;
            }
        }
    }
    __syncthreads();

    // final GEMM: 64 cols, wave = 32 rows x 32 cols
    const int cgf = (w & 1) * 2;
    f32x4 accf[2][2];
#pragma unroll
    for (int i = 0; i < 2; ++i)
#pragma unroll
        for (int j = 0; j < 2; ++j) accf[i][j] = (f32x4){0.f, 0.f, 0.f, 0.f};

#pragma unroll
    for (int ks = 0; ks < 3; ++ks) {
        const int ko = ks * 32 + g * 8;
        bf16x8 a0h = *(const bf16x8*)&Ah[(rb_base + r) * 104 + ko];
        bf16x8 a1h = *(const bf16x8*)&Ah[(rb_base + 16 + r) * 104 + ko];
        bf16x8 a0l = *(const bf16x8*)&Al[(rb_base + r) * 104 + ko];
        bf16x8 a1l = *(const bf16x8*)&Al[(rb_base + 16 + r) * 104 + ko];
        const unsigned short* bks = btl + ((size_t)(ks * 4) * 64 + lane) * 8;
#pragma unroll
        for (int ct = 0; ct < 2; ++ct) {
            const unsigned short* bp = bks + (size_t)(cgf + ct) * 512;
            bf16x8 bhv = *(const bf16x8*)bp;
            bf16x8 blv = *(const bf16x8*)(bp + BTL_PLANE);
            accf[0][ct] = __builtin_amdgcn_mfma_f32_16x16x32_bf16(a0h, bhv, accf[0][ct], 0, 0, 0);
            accf[1][ct] = __builtin_amdgcn_mfma_f32_16x16x32_bf16(a1h, bhv, accf[1][ct], 0, 0, 0);
            accf[0][ct] = __builtin_amdgcn_mfma_f32_16x16x32_bf16(a0l, bhv, accf[0][ct], 0, 0, 0);
            accf[1][ct] = __builtin_amdgcn_mfma_f32_16x16x32_bf16(a1l, bhv, accf[1][ct], 0, 0, 0);
            accf[0][ct] = __builtin_amdgcn_mfma_f32_16x16x32_bf16(a0h, blv, accf[0][ct], 0, 0, 0);
            accf[1][ct] = __builtin_amdgcn_mfma_f32_16x16x32_bf16(a1h, blv, accf[1][ct], 0, 0, 0);
        }
    }

#pragma unroll
    for (int ct = 0; ct < 2; ++ct) {
        int colc = (cgf + ct) * 16 + r;
        float bias = LB[colc];
#pragma unroll
        for (int rbi = 0; rbi < 2; ++rbi) {
            int row0 = n0 + rb_base + rbi * 16 + g * 4;
#pragma unroll
            for (int j = 0; j < 4; ++j) {
                int node = row0 + j;
                if (node < NNODES)
                    out[(size_t)node * LLDIM + colc] = accf[rbi][ct][j] + bias;
            }
        }
    }
}

extern "C" void kernel_launch(void* const* d_in, const int* in_sizes, int n_in,
                              void* d_out, int out_size, void* d_ws, size_t ws_size,
                              hipStream_t stream) {
    const float* x     = (const float*)d_in[0];
    const int*   ei    = (const int*)d_in[1];
    const int*   et    = (const int*)d_in[2];
    const float* w1    = (const float*)d_in[3];
    const float* root1 = (const float*)d_in[4];
    const float* b1    = (const float*)d_in[5];
    const float* w2    = (const float*)d_in[6];
    const float* root2 = (const float*)d_in[7];
    const float* b2    = (const float*)d_in[8];
    const float* lin_w = (const float*)d_in[9];
    const float* lin_b = (const float*)d_in[10];

    float* bufA = (float*)d_ws;                      // N*96
    float* bufB = bufA + (size_t)NNODES * DIM;       // N*96
    int* deg       = (int*)(bufB + (size_t)NNODES * DIM);
    int* row_start = deg + SCAN_N;
    int* row_end   = row_start + SCAN_N;
    int* col       = row_end + SCAN_N;               // up to NEDGES
    int* partials  = col + NEDGES;                   // 256
    unsigned short* bt = (unsigned short*)(partials + 256);

    const int edge_blocks = (NEDGES + 255) / 256;
    const int scan_blocks = (SCAN_N + 1023) / 1024;  // 147
    const int node_tiles  = (NNODES + 63) / 64;      // 782
    const int prep_blocks = (SCAN_N + 255) / 256;    // covers deg-zero + prep items

    // ---- weight prep + deg zero ----
    prep_kernel<<<prep_blocks, 256, 0, stream>>>(w1, root1, w2, root2, lin_w, bt, deg);

    // ---- CSR build ----
    hist_kernel<<<edge_blocks, 256, 0, stream>>>(ei, et, deg);
    scan1_kernel<<<scan_blocks, 256, 0, stream>>>(deg, row_start, partials, SCAN_N);
    scan2_kernel<<<1, 256, 0, stream>>>(partials, scan_blocks);
    scan3_kernel<<<(SCAN_N + 255) / 256, 256, 0, stream>>>(row_start, row_end, partials, SCAN_N);
    fill_kernel<<<edge_blocks, 256, 0, stream>>>(ei, et, row_end, col);

    // ---- Layer 0 (rel 0): x -> bufA ----
    layer_fused_kernel<<<node_tiles, 256, 0, stream>>>(
        x, row_start + 0 * NNODES, row_end + 0 * NNODES, col,
        bt + 0 * (size_t)BT_LAYER, b1, bufA);

    // ---- Layer 1 (rel 1): bufA -> bufB ----
    layer_fused_kernel<<<node_tiles, 256, 0, stream>>>(
        bufA, row_start + 1 * NNODES, row_end + 1 * NNODES, col,
        bt + 1 * (size_t)BT_LAYER, b2, bufB);

    // ---- Layer 2 (rel 2) + final linear: bufB -> d_out ----
    layer2_final_kernel<<<node_tiles, 256, 0, stream>>>(
        bufB, row_start + 2 * NNODES, row_end + 2 * NNODES, col,
        bt + 2 * (size_t)BT_LAYER, b2, bt + BT_LIN_OFF, lin_b, (float*)d_out);
}